// Round 2
// baseline (883.839 us; speedup 1.0000x reference)
//
#include <hip/hip_runtime.h>
#include <hip/hip_fp16.h>

// Problem constants
#define NB 2
#define NH 16
#define NS 2048
#define ND 64
#define BM 64
#define BN 64
#define NT (NS / BN)            // 32 K/V tiles
#define TILE_BYTES 24576        // Khi 8K + Klo 8K + Vt 8K per (bh,tile)
#define KV_BYTES ((size_t)NB * NH * NT * TILE_BYTES)   // 24 MiB workspace

// XOR swizzle: f(r) = (r&7) ^ ((r&8)>>2), applied to 16B-slot bits (4..6).
// Chosen so (a) 16-lane fragment reads (rows = n*16+lc) spread 8 slots per
// 8-lane group, and (b) Ps writes (rows r2,r2+4,r2+8,r2+12) get 4 distinct
// slots -> conflict-free.
#define SW(r) ((((r) & 7) ^ (((r) & 8) >> 2)) << 4)

typedef _Float16 half8 __attribute__((ext_vector_type(8)));
typedef _Float16 half4 __attribute__((ext_vector_type(4)));
typedef float f32x4 __attribute__((ext_vector_type(4)));

#define GLDS16(gp, lp) __builtin_amdgcn_global_load_lds(                      \
    (const __attribute__((address_space(1))) void*)(gp),                      \
    (__attribute__((address_space(3))) void*)(lp), 16, 0, 0)

// ---------------------------------------------------------------------------
// Prep: build per-(bh,tile) LDS-image blobs in workspace:
//   +0     : K hi fp16, rows=t (64), 128B/row, 16B slots XOR-swizzled
//   +8192  : K lo fp16 (residual), same layout
//   +16384 : V transposed fp16 (rows = d, cols = t), same layout
// Runs once per launch; ~34 MB read + 25 MB written ≈ 10 µs.
// ---------------------------------------------------------------------------
__global__ __launch_bounds__(256)
void prep_kv(const float* __restrict__ kg, const float* __restrict__ vg,
             char* __restrict__ ws)
{
    __shared__ _Float16 T[64][72];   // V tile staged t-major for transpose
    const int tile = blockIdx.x, bh = blockIdx.y, tid = threadIdx.x;
    const float* kp = kg + ((size_t)bh * NS + (size_t)tile * BN) * ND;
    const float* vp = vg + ((size_t)bh * NS + (size_t)tile * BN) * ND;
    char* img = ws + ((size_t)(bh * NT + tile)) * TILE_BYTES;

    // K hi/lo split (identical numerics to the in-loop split it replaces)
    #pragma unroll
    for (int i = 0; i < 2; ++i) {
        const int c = tid + i * 256;          // 512 chunks of 8 elems
        const int r = c >> 3, s = c & 7;
        const float* src = kp + r * ND + s * 8;
        float4 f0 = *(const float4*)src;
        float4 f1 = *(const float4*)(src + 4);
        float fv[8] = {f0.x, f0.y, f0.z, f0.w, f1.x, f1.y, f1.z, f1.w};
        half8 h, l;
        #pragma unroll
        for (int j = 0; j < 8; ++j) {
            _Float16 hh = (_Float16)fv[j];
            h[j] = hh; l[j] = (_Float16)(fv[j] - (float)hh);
        }
        const int off = r * 128 + ((s << 4) ^ SW(r));
        *(half8*)(img + off) = h;
        *(half8*)(img + 8192 + off) = l;
    }
    // V -> LDS (t-major), then write transposed (d-major) swizzled image
    #pragma unroll
    for (int i = 0; i < 2; ++i) {
        const int c = tid + i * 256;
        const int t = c >> 3, ds = (c & 7) * 8;
        const float* src = vp + t * ND + ds;
        float4 f0 = *(const float4*)src;
        float4 f1 = *(const float4*)(src + 4);
        float fv[8] = {f0.x, f0.y, f0.z, f0.w, f1.x, f1.y, f1.z, f1.w};
        #pragma unroll
        for (int j = 0; j < 8; ++j) T[t][ds + j] = (_Float16)fv[j];
    }
    __syncthreads();
    #pragma unroll
    for (int i = 0; i < 2; ++i) {
        const int c = tid + i * 256;
        const int d = c >> 3, s = c & 7;
        half8 h;
        #pragma unroll
        for (int j = 0; j < 8; ++j) h[j] = T[s * 8 + j][d];
        *(half8*)(img + 16384 + d * 128 + ((s << 4) ^ SW(d))) = h;
    }
}

// ---------------------------------------------------------------------------
// Main fused kernel. LDS = exactly 32 KB -> 5 blocks/CU (vs 4 before).
// Staging = pure global_load_lds (no VALU, no VGPR round-trip).
// ---------------------------------------------------------------------------
__global__ __launch_bounds__(256, 5)
void attn_fused(const float* __restrict__ qg, const char* __restrict__ kvws,
                const float* __restrict__ dwm, const float* __restrict__ sig,
                float* __restrict__ out0, float* __restrict__ attn)
{
    __shared__ char lds[32768];
    char* const Khi = lds;            // 8 KB
    char* const Klo = lds + 8192;     // 8 KB
    char* const Vs  = lds + 16384;    // 8 KB  (V^T image)
    char* const Ps  = lds + 24576;    // 8 KB  (wave-private 16-row bands)

    const int tid  = threadIdx.x;
    const int wave = tid >> 6;
    const int lane = tid & 63;
    const int quad = lane >> 4;
    const int lc   = lane & 15;

    // XCD-aware swizzle (1024 % 8 == 0 -> bijective): each XCD gets 4
    // consecutive bh values -> its K/V images (3 MB) stay L2-resident and
    // the 4 heads of one batch share the dwm slice.
    const int wg      = blockIdx.x;
    const int logical = (wg & 7) * 128 + (wg >> 3);
    const int mtile   = logical & 31;
    const int bh      = logical >> 5;
    const int b       = bh >> 4;

    const float sv = sig[0];
    const float inv_s2 = 1.0f / (sv * sv);

    const float* qp  = qg  + (size_t)bh * NS * ND + (size_t)mtile * BM * ND;
    const char*  kvb = kvws + (size_t)bh * NT * TILE_BYTES;
    const float* dp  = dwm + (size_t)b  * NS * NS + (size_t)mtile * BM * NS;
    float* op = out0 + (size_t)bh * NS * ND + (size_t)mtile * BM * ND;
    float* ap = attn + (size_t)bh * NS * NS + (size_t)mtile * BM * NS;

    // ---- Q A-fragments, hi/lo fp16 split (once per block) ----
    half8 aqh0, aql0, aqh1, aql1;
    {
        const float* qr = qp + (size_t)(wave * 16 + lc) * ND + quad * 8;
        float4 f0 = *(const float4*)qr;
        float4 f1 = *(const float4*)(qr + 4);
        float4 f2 = *(const float4*)(qr + 32);
        float4 f3 = *(const float4*)(qr + 36);
        float v0[8] = {f0.x, f0.y, f0.z, f0.w, f1.x, f1.y, f1.z, f1.w};
        float v1[8] = {f2.x, f2.y, f2.z, f2.w, f3.x, f3.y, f3.z, f3.w};
        #pragma unroll
        for (int j = 0; j < 8; j++) {
            float x = v0[j] * 0.125f;           // 1/TEMPERATURE
            _Float16 h = (_Float16)x;
            aqh0[j] = h; aql0[j] = (_Float16)(x - (float)h);
            x = v1[j] * 0.125f;
            h = (_Float16)x;
            aqh1[j] = h; aql1[j] = (_Float16)(x - (float)h);
        }
    }

    // ================= PASS A: row sums l = sum_t exp(|s*g|) ================
    float lsum[4] = {0.f, 0.f, 0.f, 0.f};

    for (int t = 0; t < NT; ++t) {
        const char* img = kvb + (size_t)t * TILE_BYTES;
        __syncthreads();
        GLDS16(img +         tid * 16, Khi +        tid * 16);
        GLDS16(img +  4096 + tid * 16, Khi + 4096 + tid * 16);
        GLDS16(img +  8192 + tid * 16, Klo +        tid * 16);
        GLDS16(img + 12288 + tid * 16, Klo + 4096 + tid * 16);
        __syncthreads();
        #pragma unroll
        for (int n = 0; n < 4; ++n) {
            const int rowK = n * 16 + lc;
            const int sw = SW(rowK);
            const char* kb = Khi + rowK * 128;
            const char* lb = Klo + rowK * 128;
            const half8 kh0 = *(const half8*)(kb + ((quad * 16) ^ sw));
            const half8 kh1 = *(const half8*)(kb + ((64 + quad * 16) ^ sw));
            const half8 kl0 = *(const half8*)(lb + ((quad * 16) ^ sw));
            const half8 kl1 = *(const half8*)(lb + ((64 + quad * 16) ^ sw));
            f32x4 c = {0.f, 0.f, 0.f, 0.f};
            c = __builtin_amdgcn_mfma_f32_16x16x32_f16(aqh0, kh0, c, 0, 0, 0);
            c = __builtin_amdgcn_mfma_f32_16x16x32_f16(aqh1, kh1, c, 0, 0, 0);
            c = __builtin_amdgcn_mfma_f32_16x16x32_f16(aql0, kh0, c, 0, 0, 0);
            c = __builtin_amdgcn_mfma_f32_16x16x32_f16(aql1, kh1, c, 0, 0, 0);
            c = __builtin_amdgcn_mfma_f32_16x16x32_f16(aqh0, kl0, c, 0, 0, 0);
            c = __builtin_amdgcn_mfma_f32_16x16x32_f16(aqh1, kl1, c, 0, 0, 0);
            #pragma unroll
            for (int r2 = 0; r2 < 4; ++r2) {
                const int lrow = wave * 16 + quad * 4 + r2;
                const int col  = t * BN + n * 16 + lc;
                const float g = __expf(dp[(size_t)lrow * NS + col] * inv_s2);
                lsum[r2] += __expf(fabsf(c[r2]) * g);   // z <= ~16: fp32-safe
            }
        }
    }

    #pragma unroll
    for (int r2 = 0; r2 < 4; ++r2) {
        float s = lsum[r2];
        s += __shfl_xor(s, 1, 64);
        s += __shfl_xor(s, 2, 64);
        s += __shfl_xor(s, 4, 64);
        s += __shfl_xor(s, 8, 64);
        lsum[r2] = 1.0f / s;   // 1/l
    }

    // ============ PASS B: recompute scores, write attn, O += P*V ===========
    f32x4 o[4];
    #pragma unroll
    for (int i = 0; i < 4; i++) o[i] = (f32x4){0.f, 0.f, 0.f, 0.f};

    for (int t = 0; t < NT; ++t) {
        const char* img = kvb + (size_t)t * TILE_BYTES;
        __syncthreads();
        GLDS16(img +         tid * 16, Khi +        tid * 16);
        GLDS16(img +  4096 + tid * 16, Khi + 4096 + tid * 16);
        GLDS16(img +  8192 + tid * 16, Klo +        tid * 16);
        GLDS16(img + 12288 + tid * 16, Klo + 4096 + tid * 16);
        GLDS16(img + 16384 + tid * 16, Vs  +        tid * 16);
        GLDS16(img + 20480 + tid * 16, Vs  + 4096 + tid * 16);
        __syncthreads();
        #pragma unroll
        for (int n = 0; n < 4; ++n) {
            const int rowK = n * 16 + lc;
            const int sw = SW(rowK);
            const char* kb = Khi + rowK * 128;
            const char* lb = Klo + rowK * 128;
            const half8 kh0 = *(const half8*)(kb + ((quad * 16) ^ sw));
            const half8 kh1 = *(const half8*)(kb + ((64 + quad * 16) ^ sw));
            const half8 kl0 = *(const half8*)(lb + ((quad * 16) ^ sw));
            const half8 kl1 = *(const half8*)(lb + ((64 + quad * 16) ^ sw));
            f32x4 c = {0.f, 0.f, 0.f, 0.f};
            c = __builtin_amdgcn_mfma_f32_16x16x32_f16(aqh0, kh0, c, 0, 0, 0);
            c = __builtin_amdgcn_mfma_f32_16x16x32_f16(aqh1, kh1, c, 0, 0, 0);
            c = __builtin_amdgcn_mfma_f32_16x16x32_f16(aql0, kh0, c, 0, 0, 0);
            c = __builtin_amdgcn_mfma_f32_16x16x32_f16(aql1, kh1, c, 0, 0, 0);
            c = __builtin_amdgcn_mfma_f32_16x16x32_f16(aqh0, kl0, c, 0, 0, 0);
            c = __builtin_amdgcn_mfma_f32_16x16x32_f16(aqh1, kl1, c, 0, 0, 0);
            #pragma unroll
            for (int r2 = 0; r2 < 4; ++r2) {
                const int lrow = wave * 16 + quad * 4 + r2;
                const int col  = t * BN + n * 16 + lc;
                const float g = __expf(dp[(size_t)lrow * NS + col] * inv_s2);
                const float p = __expf(fabsf(c[r2]) * g) * lsum[r2];
                *(_Float16*)(Ps + lrow * 128 +
                             (((n * 16 + lc) * 2) ^ SW(lrow))) = (_Float16)p;
            }
        }
        // P: C-layout -> A-layout via wave-private swizzled band (no barrier)
        const int rowP = wave * 16 + lc;
        const int swp = SW(rowP);
        const half8 pa0 = *(const half8*)(Ps + rowP * 128 + ((quad * 16) ^ swp));
        const half8 pa1 = *(const half8*)(Ps + rowP * 128 + ((64 + quad * 16) ^ swp));

        // attn store: 16 lanes cover one row's 64 cols -> 256B contiguous runs
        {
            const int cl = lane & 15, rh = lane >> 4;
            #pragma unroll
            for (int g2 = 0; g2 < 4; ++g2) {
                const int row = wave * 16 + g2 * 4 + rh;
                const half4 ph = *(const half4*)(Ps + row * 128 +
                                                 ((cl * 8) ^ SW(row)));
                f32x4 s = {(float)ph[0], (float)ph[1], (float)ph[2], (float)ph[3]};
                __builtin_nontemporal_store(
                    s, (f32x4*)(ap + (size_t)row * NS + t * BN + cl * 4));
            }
        }

        #pragma unroll
        for (int n2 = 0; n2 < 4; ++n2) {
            const int dv = n2 * 16 + lc;
            const int swv = SW(dv);
            const char* vb = Vs + dv * 128;
            const half8 bv0 = *(const half8*)(vb + ((quad * 16) ^ swv));
            const half8 bv1 = *(const half8*)(vb + ((64 + quad * 16) ^ swv));
            o[n2] = __builtin_amdgcn_mfma_f32_16x16x32_f16(pa0, bv0, o[n2], 0, 0, 0);
            o[n2] = __builtin_amdgcn_mfma_f32_16x16x32_f16(pa1, bv1, o[n2], 0, 0, 0);
        }
    }

    // ---- epilogue: write O ----
    #pragma unroll
    for (int n2 = 0; n2 < 4; ++n2) {
        #pragma unroll
        for (int r2 = 0; r2 < 4; ++r2) {
            const int lrow = wave * 16 + quad * 4 + r2;
            __builtin_nontemporal_store(o[n2][r2],
                                        &op[(size_t)lrow * ND + n2 * 16 + lc]);
        }
    }
}

// ---------------------------------------------------------------------------
// Legacy fallback (previous verified kernel, verbatim) — used only if the
// provided workspace is too small for the KV tile images.
// ---------------------------------------------------------------------------
#define KP 72
#define VP 72
#define PP 72

__global__ __launch_bounds__(256, 4)
void attn_fused_legacy(const float* __restrict__ qg, const float* __restrict__ kgl,
                       const float* __restrict__ vgl, const float* __restrict__ dwm,
                       const float* __restrict__ sig, float* __restrict__ out0,
                       float* __restrict__ attn)
{
    __shared__ _Float16 Khi[BN * KP];
    __shared__ _Float16 Klo[BN * KP];
    __shared__ _Float16 Vsl[ND * VP];
    __shared__ _Float16 Psl[BM * PP];

    const int tid  = threadIdx.x;
    const int wave = tid >> 6;
    const int lane = tid & 63;
    const int quad = lane >> 4;
    const int lc   = lane & 15;

    const int mtile = blockIdx.x;
    const int bh    = blockIdx.y;
    const int b     = bh >> 4;

    const float sv = sig[0];
    const float inv_s2 = 1.0f / (sv * sv);

    const float* qp = qg  + (size_t)bh * NS * ND + (size_t)mtile * BM * ND;
    const float* kp = kgl + (size_t)bh * NS * ND;
    const float* vp = vgl + (size_t)bh * NS * ND;
    const float* dp = dwm + (size_t)b  * NS * NS + (size_t)mtile * BM * NS;
    float* op = out0 + (size_t)bh * NS * ND + (size_t)mtile * BM * ND;
    float* ap = attn + (size_t)bh * NS * NS + (size_t)mtile * BM * NS;

    half8 aqh0, aql0, aqh1, aql1;
    {
        const float* qr = qp + (size_t)(wave * 16 + lc) * ND + quad * 8;
        float4 f0 = *(const float4*)qr;
        float4 f1 = *(const float4*)(qr + 4);
        float4 f2 = *(const float4*)(qr + 32);
        float4 f3 = *(const float4*)(qr + 36);
        float v0[8] = {f0.x, f0.y, f0.z, f0.w, f1.x, f1.y, f1.z, f1.w};
        float v1[8] = {f2.x, f2.y, f2.z, f2.w, f3.x, f3.y, f3.z, f3.w};
        #pragma unroll
        for (int j = 0; j < 8; j++) {
            float x = v0[j] * 0.125f;
            _Float16 h = (_Float16)x;
            aqh0[j] = h; aql0[j] = (_Float16)(x - (float)h);
            x = v1[j] * 0.125f;
            h = (_Float16)x;
            aqh1[j] = h; aql1[j] = (_Float16)(x - (float)h);
        }
    }

    auto stageK = [&](int t0) {
        const int r  = tid >> 2;
        const int ds = (tid & 3) * 16;
        const float* s = kp + (size_t)(t0 + r) * ND + ds;
        float4 f0 = *(const float4*)s;
        float4 f1 = *(const float4*)(s + 4);
        float4 f2 = *(const float4*)(s + 8);
        float4 f3 = *(const float4*)(s + 12);
        float fv[16] = {f0.x, f0.y, f0.z, f0.w, f1.x, f1.y, f1.z, f1.w,
                        f2.x, f2.y, f2.z, f2.w, f3.x, f3.y, f3.z, f3.w};
        half8 h0, h1, l0, l1;
        #pragma unroll
        for (int i = 0; i < 8; i++) {
            _Float16 h = (_Float16)fv[i];
            h0[i] = h; l0[i] = (_Float16)(fv[i] - (float)h);
            h = (_Float16)fv[8 + i];
            h1[i] = h; l1[i] = (_Float16)(fv[8 + i] - (float)h);
        }
        *(half8*)&Khi[r * KP + ds]     = h0;
        *(half8*)&Khi[r * KP + ds + 8] = h1;
        *(half8*)&Klo[r * KP + ds]     = l0;
        *(half8*)&Klo[r * KP + ds + 8] = l1;
    };

    auto stageV = [&](int t0) {
        const int tp = tid >> 3;
        const int ds = (tid & 7) * 8;
        const float4* sa = (const float4*)(vp + (size_t)(t0 + 2 * tp) * ND + ds);
        const float4* sb = (const float4*)(vp + (size_t)(t0 + 2 * tp + 1) * ND + ds);
        float4 a0 = sa[0], a1 = sa[1];
        float4 b0 = sb[0], b1 = sb[1];
        float av[8] = {a0.x, a0.y, a0.z, a0.w, a1.x, a1.y, a1.z, a1.w};
        float bv[8] = {b0.x, b0.y, b0.z, b0.w, b1.x, b1.y, b1.z, b1.w};
        unsigned int* Vdw = (unsigned int*)Vsl;
        #pragma unroll
        for (int i = 0; i < 8; i++) {
            const int d  = ds + i;
            const int dw = d * (VP / 2) + (tp ^ (((d >> 3) & 7) << 2));
            union { _Float16 h[2]; unsigned int u; } pk;
            pk.h[0] = (_Float16)av[i];
            pk.h[1] = (_Float16)bv[i];
            Vdw[dw] = pk.u;
        }
    };

    float lsum[4] = {0.f, 0.f, 0.f, 0.f};

    for (int t0 = 0; t0 < NS; t0 += BN) {
        __syncthreads();
        stageK(t0);
        __syncthreads();
        #pragma unroll
        for (int n = 0; n < 4; n++) {
            const half8 kh0 = *(const half8*)&Khi[(n * 16 + lc) * KP + quad * 8];
            const half8 kh1 = *(const half8*)&Khi[(n * 16 + lc) * KP + quad * 8 + 32];
            const half8 kl0 = *(const half8*)&Klo[(n * 16 + lc) * KP + quad * 8];
            const half8 kl1 = *(const half8*)&Klo[(n * 16 + lc) * KP + quad * 8 + 32];
            f32x4 c = {0.f, 0.f, 0.f, 0.f};
            c = __builtin_amdgcn_mfma_f32_16x16x32_f16(aqh0, kh0, c, 0, 0, 0);
            c = __builtin_amdgcn_mfma_f32_16x16x32_f16(aqh1, kh1, c, 0, 0, 0);
            c = __builtin_amdgcn_mfma_f32_16x16x32_f16(aql0, kh0, c, 0, 0, 0);
            c = __builtin_amdgcn_mfma_f32_16x16x32_f16(aql1, kh1, c, 0, 0, 0);
            c = __builtin_amdgcn_mfma_f32_16x16x32_f16(aqh0, kl0, c, 0, 0, 0);
            c = __builtin_amdgcn_mfma_f32_16x16x32_f16(aqh1, kl1, c, 0, 0, 0);
            #pragma unroll
            for (int r2 = 0; r2 < 4; r2++) {
                const int lrow = wave * 16 + quad * 4 + r2;
                const int col  = t0 + n * 16 + lc;
                const float g = __expf(dp[(size_t)lrow * NS + col] * inv_s2);
                const float z = fabsf(c[r2] * g);
                lsum[r2] += __expf(z);
            }
        }
    }

    #pragma unroll
    for (int r2 = 0; r2 < 4; r2++) {
        float s = lsum[r2];
        s += __shfl_xor(s, 1, 64);
        s += __shfl_xor(s, 2, 64);
        s += __shfl_xor(s, 4, 64);
        s += __shfl_xor(s, 8, 64);
        lsum[r2] = 1.0f / s;
    }

    f32x4 o[4];
    #pragma unroll
    for (int i = 0; i < 4; i++) o[i] = (f32x4){0.f, 0.f, 0.f, 0.f};

    for (int t0 = 0; t0 < NS; t0 += BN) {
        __syncthreads();
        stageK(t0);
        stageV(t0);
        __syncthreads();
        #pragma unroll
        for (int n = 0; n < 4; n++) {
            const half8 kh0 = *(const half8*)&Khi[(n * 16 + lc) * KP + quad * 8];
            const half8 kh1 = *(const half8*)&Khi[(n * 16 + lc) * KP + quad * 8 + 32];
            const half8 kl0 = *(const half8*)&Klo[(n * 16 + lc) * KP + quad * 8];
            const half8 kl1 = *(const half8*)&Klo[(n * 16 + lc) * KP + quad * 8 + 32];
            f32x4 c = {0.f, 0.f, 0.f, 0.f};
            c = __builtin_amdgcn_mfma_f32_16x16x32_f16(aqh0, kh0, c, 0, 0, 0);
            c = __builtin_amdgcn_mfma_f32_16x16x32_f16(aqh1, kh1, c, 0, 0, 0);
            c = __builtin_amdgcn_mfma_f32_16x16x32_f16(aql0, kh0, c, 0, 0, 0);
            c = __builtin_amdgcn_mfma_f32_16x16x32_f16(aql1, kh1, c, 0, 0, 0);
            c = __builtin_amdgcn_mfma_f32_16x16x32_f16(aqh0, kl0, c, 0, 0, 0);
            c = __builtin_amdgcn_mfma_f32_16x16x32_f16(aqh1, kl1, c, 0, 0, 0);
            #pragma unroll
            for (int r2 = 0; r2 < 4; r2++) {
                const int lrow = wave * 16 + quad * 4 + r2;
                const int col  = t0 + n * 16 + lc;
                const float g = __expf(dp[(size_t)lrow * NS + col] * inv_s2);
                const float z = fabsf(c[r2] * g);
                const float p = __expf(z) * lsum[r2];
                Psl[(size_t)lrow * PP + n * 16 + lc] = (_Float16)p;
            }
        }
        const half8 pa0 = *(const half8*)&Psl[(wave * 16 + lc) * PP + quad * 8];
        const half8 pa1 = *(const half8*)&Psl[(wave * 16 + lc) * PP + quad * 8 + 32];

        {
            float* arow = ap + (size_t)(wave * 16 + lc) * NS + t0 + quad * 8;
            f32x4 s0 = {(float)pa0[0], (float)pa0[1], (float)pa0[2], (float)pa0[3]};
            f32x4 s1 = {(float)pa0[4], (float)pa0[5], (float)pa0[6], (float)pa0[7]};
            f32x4 s2 = {(float)pa1[0], (float)pa1[1], (float)pa1[2], (float)pa1[3]};
            f32x4 s3 = {(float)pa1[4], (float)pa1[5], (float)pa1[6], (float)pa1[7]};
            __builtin_nontemporal_store(s0, (f32x4*)arow);
            __builtin_nontemporal_store(s1, (f32x4*)(arow + 4));
            __builtin_nontemporal_store(s2, (f32x4*)(arow + 32));
            __builtin_nontemporal_store(s3, (f32x4*)(arow + 36));
        }

        #pragma unroll
        for (int n2 = 0; n2 < 4; n2++) {
            const int dv  = n2 * 16 + lc;
            const int fd  = ((dv >> 3) & 7) << 2;
            const int dwb = dv * (VP / 2);
            const half8 bv0 = *(const half8*)((const char*)Vsl +
                               (size_t)((dwb + ((quad * 4) ^ fd)) * 4));
            const half8 bv1 = *(const half8*)((const char*)Vsl +
                               (size_t)((dwb + ((16 + quad * 4) ^ fd)) * 4));
            o[n2] = __builtin_amdgcn_mfma_f32_16x16x32_f16(pa0, bv0, o[n2], 0, 0, 0);
            o[n2] = __builtin_amdgcn_mfma_f32_16x16x32_f16(pa1, bv1, o[n2], 0, 0, 0);
        }
    }

    #pragma unroll
    for (int n2 = 0; n2 < 4; n2++) {
        #pragma unroll
        for (int r2 = 0; r2 < 4; r2++) {
            const int lrow = wave * 16 + quad * 4 + r2;
            __builtin_nontemporal_store(o[n2][r2],
                                        &op[(size_t)lrow * ND + n2 * 16 + lc]);
        }
    }
}

extern "C" void kernel_launch(void* const* d_in, const int* in_sizes, int n_in,
                              void* d_out, int out_size, void* d_ws, size_t ws_size,
                              hipStream_t stream) {
    (void)in_sizes; (void)n_in; (void)out_size;
    const float* q   = (const float*)d_in[0];
    const float* k   = (const float*)d_in[1];
    const float* v   = (const float*)d_in[2];
    const float* dwm = (const float*)d_in[3];
    const float* sig = (const float*)d_in[4];
    float* out0 = (float*)d_out;
    float* attn = out0 + (size_t)NB * NH * NS * ND;

    if (d_ws != nullptr && ws_size >= KV_BYTES) {
        char* ws = (char*)d_ws;
        prep_kv<<<dim3(NT, NB * NH), dim3(256), 0, stream>>>(k, v, ws);
        attn_fused<<<dim3(NT * NB * NH), dim3(256), 0, stream>>>(
            q, ws, dwm, sig, out0, attn);
    } else {
        dim3 grid(NS / BM, NB * NH);
        attn_fused_legacy<<<grid, dim3(256), 0, stream>>>(
            q, k, v, dwm, sig, out0, attn);
    }
}

// Round 3
// 864.872 us; speedup vs baseline: 1.0219x; 1.0219x over previous
//
#include <hip/hip_runtime.h>
#include <hip/hip_fp16.h>

// Problem constants
#define NB 2
#define NH 16
#define NS 2048
#define ND 64
#define BM 64
#define BN 64
#define NT (NS / BN)            // 32 K/V tiles
#define TILE_BYTES 24576        // Khi 8K + Klo 8K + Vt 8K per (bh,tile)
#define KV_BYTES ((size_t)NB * NH * NT * TILE_BYTES)   // 24 MiB workspace

// XOR swizzle: f(r) = (r&7) ^ ((r&8)>>2), applied to 16B-slot bits (4..6).
// (a) 16-lane fragment reads (rows = n*16+lc) spread 8 slots per 8-lane
// group, and (b) Ps writes (rows r2,r2+4,r2+8,r2+12) get 4 distinct slots
// -> conflict-free (verified: SQ_LDS_BANK_CONFLICT == 0 in round 2).
#define SW(r) ((((r) & 7) ^ (((r) & 8) >> 2)) << 4)

typedef _Float16 half8 __attribute__((ext_vector_type(8)));
typedef _Float16 half4 __attribute__((ext_vector_type(4)));
typedef float f32x4 __attribute__((ext_vector_type(4)));

#define GLDS16(gp, lp) __builtin_amdgcn_global_load_lds(                      \
    (const __attribute__((address_space(1))) void*)(gp),                      \
    (__attribute__((address_space(3))) void*)(lp), 16, 0, 0)

// ---------------------------------------------------------------------------
// Prep: build per-(bh,tile) LDS-image blobs in workspace:
//   +0     : K hi fp16, rows=t (64), 128B/row, 16B slots XOR-swizzled
//   +8192  : K lo fp16 (residual), same layout
//   +16384 : V transposed fp16 (rows = d, cols = t), same layout
// ---------------------------------------------------------------------------
__global__ __launch_bounds__(256)
void prep_kv(const float* __restrict__ kg, const float* __restrict__ vg,
             char* __restrict__ ws)
{
    __shared__ _Float16 T[64][72];   // V tile staged t-major for transpose
    const int tile = blockIdx.x, bh = blockIdx.y, tid = threadIdx.x;
    const float* kp = kg + ((size_t)bh * NS + (size_t)tile * BN) * ND;
    const float* vp = vg + ((size_t)bh * NS + (size_t)tile * BN) * ND;
    char* img = ws + ((size_t)(bh * NT + tile)) * TILE_BYTES;

    // K hi/lo split (identical numerics to the in-loop split it replaces)
    #pragma unroll
    for (int i = 0; i < 2; ++i) {
        const int c = tid + i * 256;          // 512 chunks of 8 elems
        const int r = c >> 3, s = c & 7;
        const float* src = kp + r * ND + s * 8;
        float4 f0 = *(const float4*)src;
        float4 f1 = *(const float4*)(src + 4);
        float fv[8] = {f0.x, f0.y, f0.z, f0.w, f1.x, f1.y, f1.z, f1.w};
        half8 h, l;
        #pragma unroll
        for (int j = 0; j < 8; ++j) {
            _Float16 hh = (_Float16)fv[j];
            h[j] = hh; l[j] = (_Float16)(fv[j] - (float)hh);
        }
        const int off = r * 128 + ((s << 4) ^ SW(r));
        *(half8*)(img + off) = h;
        *(half8*)(img + 8192 + off) = l;
    }
    // V -> LDS (t-major), then write transposed (d-major) swizzled image
    #pragma unroll
    for (int i = 0; i < 2; ++i) {
        const int c = tid + i * 256;
        const int t = c >> 3, ds = (c & 7) * 8;
        const float* src = vp + t * ND + ds;
        float4 f0 = *(const float4*)src;
        float4 f1 = *(const float4*)(src + 4);
        float fv[8] = {f0.x, f0.y, f0.z, f0.w, f1.x, f1.y, f1.z, f1.w};
        #pragma unroll
        for (int j = 0; j < 8; ++j) T[t][ds + j] = (_Float16)fv[j];
    }
    __syncthreads();
    #pragma unroll
    for (int i = 0; i < 2; ++i) {
        const int c = tid + i * 256;
        const int d = c >> 3, s = c & 7;
        half8 h;
        #pragma unroll
        for (int j = 0; j < 8; ++j) h[j] = T[s * 8 + j][d];
        *(half8*)(img + 16384 + d * 128 + ((s << 4) ^ SW(d))) = h;
    }
}

// ---------------------------------------------------------------------------
// Main fused kernel.
// Grid: natural 2D (x=mtile, y=bh). linear = mtile + 32*bh and 32*bh ≡ 0
// (mod 8) -> XCD k naturally gets mtiles ≡ k (mod 8) across ALL heads:
// dwm working set per XCD = 8 bands * 512KB = 4MB = L2, with 16-head reuse.
// (Round-2's bh-grouped swizzle thrashed L2 on dwm: FETCH 239->615 MB.)
// Staging = pure global_load_lds (no VALU, no VGPR round-trip), 0 conflicts.
// ---------------------------------------------------------------------------
__global__ __launch_bounds__(256, 5)
void attn_fused(const float* __restrict__ qg, const char* __restrict__ kvws,
                const float* __restrict__ dwm, const float* __restrict__ sig,
                float* __restrict__ out0, float* __restrict__ attn)
{
    __shared__ char lds[32768];
    char* const Khi = lds;            // 8 KB
    char* const Klo = lds + 8192;     // 8 KB
    char* const Vs  = lds + 16384;    // 8 KB  (V^T image)
    char* const Ps  = lds + 24576;    // 8 KB  (wave-private 16-row bands)

    const int tid  = threadIdx.x;
    const int wave = tid >> 6;
    const int lane = tid & 63;
    const int quad = lane >> 4;
    const int lc   = lane & 15;

    const int mtile = blockIdx.x;   // 0..31 row tiles
    const int bh    = blockIdx.y;   // 0..31 (b,h)
    const int b     = bh >> 4;

    const float sv = sig[0];
    const float inv_s2 = 1.0f / (sv * sv);

    const float* qp  = qg  + (size_t)bh * NS * ND + (size_t)mtile * BM * ND;
    const char*  kvb = kvws + (size_t)bh * NT * TILE_BYTES;
    const float* dp  = dwm + (size_t)b  * NS * NS + (size_t)mtile * BM * NS;
    float* op = out0 + (size_t)bh * NS * ND + (size_t)mtile * BM * ND;
    float* ap = attn + (size_t)bh * NS * NS + (size_t)mtile * BM * NS;

    // ---- Q A-fragments, hi/lo fp16 split (once per block) ----
    half8 aqh0, aql0, aqh1, aql1;
    {
        const float* qr = qp + (size_t)(wave * 16 + lc) * ND + quad * 8;
        float4 f0 = *(const float4*)qr;
        float4 f1 = *(const float4*)(qr + 4);
        float4 f2 = *(const float4*)(qr + 32);
        float4 f3 = *(const float4*)(qr + 36);
        float v0[8] = {f0.x, f0.y, f0.z, f0.w, f1.x, f1.y, f1.z, f1.w};
        float v1[8] = {f2.x, f2.y, f2.z, f2.w, f3.x, f3.y, f3.z, f3.w};
        #pragma unroll
        for (int j = 0; j < 8; j++) {
            float x = v0[j] * 0.125f;           // 1/TEMPERATURE
            _Float16 h = (_Float16)x;
            aqh0[j] = h; aql0[j] = (_Float16)(x - (float)h);
            x = v1[j] * 0.125f;
            h = (_Float16)x;
            aqh1[j] = h; aql1[j] = (_Float16)(x - (float)h);
        }
    }

    // ================= PASS A: row sums l = sum_t exp(|s*g|) ================
    float lsum[4] = {0.f, 0.f, 0.f, 0.f};

    for (int t = 0; t < NT; ++t) {
        const char* img = kvb + (size_t)t * TILE_BYTES;
        __syncthreads();
        GLDS16(img +         tid * 16, Khi +        tid * 16);
        GLDS16(img +  4096 + tid * 16, Khi + 4096 + tid * 16);
        GLDS16(img +  8192 + tid * 16, Klo +        tid * 16);
        GLDS16(img + 12288 + tid * 16, Klo + 4096 + tid * 16);
        __syncthreads();
        #pragma unroll
        for (int n = 0; n < 4; ++n) {
            const int rowK = n * 16 + lc;
            const int sw = SW(rowK);
            const char* kb = Khi + rowK * 128;
            const char* lb = Klo + rowK * 128;
            const half8 kh0 = *(const half8*)(kb + ((quad * 16) ^ sw));
            const half8 kh1 = *(const half8*)(kb + ((64 + quad * 16) ^ sw));
            const half8 kl0 = *(const half8*)(lb + ((quad * 16) ^ sw));
            const half8 kl1 = *(const half8*)(lb + ((64 + quad * 16) ^ sw));
            f32x4 c = {0.f, 0.f, 0.f, 0.f};
            c = __builtin_amdgcn_mfma_f32_16x16x32_f16(aqh0, kh0, c, 0, 0, 0);
            c = __builtin_amdgcn_mfma_f32_16x16x32_f16(aqh1, kh1, c, 0, 0, 0);
            c = __builtin_amdgcn_mfma_f32_16x16x32_f16(aql0, kh0, c, 0, 0, 0);
            c = __builtin_amdgcn_mfma_f32_16x16x32_f16(aql1, kh1, c, 0, 0, 0);
            c = __builtin_amdgcn_mfma_f32_16x16x32_f16(aqh0, kl0, c, 0, 0, 0);
            c = __builtin_amdgcn_mfma_f32_16x16x32_f16(aqh1, kl1, c, 0, 0, 0);
            #pragma unroll
            for (int r2 = 0; r2 < 4; ++r2) {
                const int lrow = wave * 16 + quad * 4 + r2;
                const int col  = t * BN + n * 16 + lc;
                const float g = __expf(dp[(size_t)lrow * NS + col] * inv_s2);
                lsum[r2] += __expf(fabsf(c[r2]) * g);   // z <= ~16: fp32-safe
            }
        }
    }

    #pragma unroll
    for (int r2 = 0; r2 < 4; ++r2) {
        float s = lsum[r2];
        s += __shfl_xor(s, 1, 64);
        s += __shfl_xor(s, 2, 64);
        s += __shfl_xor(s, 4, 64);
        s += __shfl_xor(s, 8, 64);
        lsum[r2] = 1.0f / s;   // 1/l
    }

    // ============ PASS B: recompute scores, write attn, O += P*V ===========
    f32x4 o[4];
    #pragma unroll
    for (int i = 0; i < 4; i++) o[i] = (f32x4){0.f, 0.f, 0.f, 0.f};

    for (int t = 0; t < NT; ++t) {
        const char* img = kvb + (size_t)t * TILE_BYTES;
        __syncthreads();
        GLDS16(img +         tid * 16, Khi +        tid * 16);
        GLDS16(img +  4096 + tid * 16, Khi + 4096 + tid * 16);
        GLDS16(img +  8192 + tid * 16, Klo +        tid * 16);
        GLDS16(img + 12288 + tid * 16, Klo + 4096 + tid * 16);
        GLDS16(img + 16384 + tid * 16, Vs  +        tid * 16);
        GLDS16(img + 20480 + tid * 16, Vs  + 4096 + tid * 16);
        __syncthreads();
        #pragma unroll
        for (int n = 0; n < 4; ++n) {
            const int rowK = n * 16 + lc;
            const int sw = SW(rowK);
            const char* kb = Khi + rowK * 128;
            const char* lb = Klo + rowK * 128;
            const half8 kh0 = *(const half8*)(kb + ((quad * 16) ^ sw));
            const half8 kh1 = *(const half8*)(kb + ((64 + quad * 16) ^ sw));
            const half8 kl0 = *(const half8*)(lb + ((quad * 16) ^ sw));
            const half8 kl1 = *(const half8*)(lb + ((64 + quad * 16) ^ sw));
            f32x4 c = {0.f, 0.f, 0.f, 0.f};
            c = __builtin_amdgcn_mfma_f32_16x16x32_f16(aqh0, kh0, c, 0, 0, 0);
            c = __builtin_amdgcn_mfma_f32_16x16x32_f16(aqh1, kh1, c, 0, 0, 0);
            c = __builtin_amdgcn_mfma_f32_16x16x32_f16(aql0, kh0, c, 0, 0, 0);
            c = __builtin_amdgcn_mfma_f32_16x16x32_f16(aql1, kh1, c, 0, 0, 0);
            c = __builtin_amdgcn_mfma_f32_16x16x32_f16(aqh0, kl0, c, 0, 0, 0);
            c = __builtin_amdgcn_mfma_f32_16x16x32_f16(aqh1, kl1, c, 0, 0, 0);
            #pragma unroll
            for (int r2 = 0; r2 < 4; ++r2) {
                const int lrow = wave * 16 + quad * 4 + r2;
                const int col  = t * BN + n * 16 + lc;
                const float g = __expf(dp[(size_t)lrow * NS + col] * inv_s2);
                const float p = __expf(fabsf(c[r2]) * g) * lsum[r2];
                *(_Float16*)(Ps + lrow * 128 +
                             (((n * 16 + lc) * 2) ^ SW(lrow))) = (_Float16)p;
            }
        }
        // P: C-layout -> A-layout via wave-private swizzled band (no barrier)
        const int rowP = wave * 16 + lc;
        const int swp = SW(rowP);
        const half8 pa0 = *(const half8*)(Ps + rowP * 128 + ((quad * 16) ^ swp));
        const half8 pa1 = *(const half8*)(Ps + rowP * 128 + ((64 + quad * 16) ^ swp));

        // attn store: 16 lanes cover one row's 64 cols -> 256B contiguous runs
        {
            const int cl = lane & 15, rh = lane >> 4;
            #pragma unroll
            for (int g2 = 0; g2 < 4; ++g2) {
                const int row = wave * 16 + g2 * 4 + rh;
                const half4 ph = *(const half4*)(Ps + row * 128 +
                                                 ((cl * 8) ^ SW(row)));
                f32x4 s = {(float)ph[0], (float)ph[1], (float)ph[2], (float)ph[3]};
                __builtin_nontemporal_store(
                    s, (f32x4*)(ap + (size_t)row * NS + t * BN + cl * 4));
            }
        }

        #pragma unroll
        for (int n2 = 0; n2 < 4; ++n2) {
            const int dv = n2 * 16 + lc;
            const int swv = SW(dv);
            const char* vb = Vs + dv * 128;
            const half8 bv0 = *(const half8*)(vb + ((quad * 16) ^ swv));
            const half8 bv1 = *(const half8*)(vb + ((64 + quad * 16) ^ swv));
            o[n2] = __builtin_amdgcn_mfma_f32_16x16x32_f16(pa0, bv0, o[n2], 0, 0, 0);
            o[n2] = __builtin_amdgcn_mfma_f32_16x16x32_f16(pa1, bv1, o[n2], 0, 0, 0);
        }
    }

    // ---- epilogue: write O ----
    #pragma unroll
    for (int n2 = 0; n2 < 4; ++n2) {
        #pragma unroll
        for (int r2 = 0; r2 < 4; ++r2) {
            const int lrow = wave * 16 + quad * 4 + r2;
            __builtin_nontemporal_store(o[n2][r2],
                                        &op[(size_t)lrow * ND + n2 * 16 + lc]);
        }
    }
}

// ---------------------------------------------------------------------------
// Legacy fallback (previous verified kernel, verbatim) — used only if the
// provided workspace is too small for the KV tile images.
// ---------------------------------------------------------------------------
#define KP 72
#define VP 72
#define PP 72

__global__ __launch_bounds__(256, 4)
void attn_fused_legacy(const float* __restrict__ qg, const float* __restrict__ kgl,
                       const float* __restrict__ vgl, const float* __restrict__ dwm,
                       const float* __restrict__ sig, float* __restrict__ out0,
                       float* __restrict__ attn)
{
    __shared__ _Float16 Khi[BN * KP];
    __shared__ _Float16 Klo[BN * KP];
    __shared__ _Float16 Vsl[ND * VP];
    __shared__ _Float16 Psl[BM * PP];

    const int tid  = threadIdx.x;
    const int wave = tid >> 6;
    const int lane = tid & 63;
    const int quad = lane >> 4;
    const int lc   = lane & 15;

    const int mtile = blockIdx.x;
    const int bh    = blockIdx.y;
    const int b     = bh >> 4;

    const float sv = sig[0];
    const float inv_s2 = 1.0f / (sv * sv);

    const float* qp = qg  + (size_t)bh * NS * ND + (size_t)mtile * BM * ND;
    const float* kp = kgl + (size_t)bh * NS * ND;
    const float* vp = vgl + (size_t)bh * NS * ND;
    const float* dp = dwm + (size_t)b  * NS * NS + (size_t)mtile * BM * NS;
    float* op = out0 + (size_t)bh * NS * ND + (size_t)mtile * BM * ND;
    float* ap = attn + (size_t)bh * NS * NS + (size_t)mtile * BM * NS;

    half8 aqh0, aql0, aqh1, aql1;
    {
        const float* qr = qp + (size_t)(wave * 16 + lc) * ND + quad * 8;
        float4 f0 = *(const float4*)qr;
        float4 f1 = *(const float4*)(qr + 4);
        float4 f2 = *(const float4*)(qr + 32);
        float4 f3 = *(const float4*)(qr + 36);
        float v0[8] = {f0.x, f0.y, f0.z, f0.w, f1.x, f1.y, f1.z, f1.w};
        float v1[8] = {f2.x, f2.y, f2.z, f2.w, f3.x, f3.y, f3.z, f3.w};
        #pragma unroll
        for (int j = 0; j < 8; j++) {
            float x = v0[j] * 0.125f;
            _Float16 h = (_Float16)x;
            aqh0[j] = h; aql0[j] = (_Float16)(x - (float)h);
            x = v1[j] * 0.125f;
            h = (_Float16)x;
            aqh1[j] = h; aql1[j] = (_Float16)(x - (float)h);
        }
    }

    auto stageK = [&](int t0) {
        const int r  = tid >> 2;
        const int ds = (tid & 3) * 16;
        const float* s = kp + (size_t)(t0 + r) * ND + ds;
        float4 f0 = *(const float4*)s;
        float4 f1 = *(const float4*)(s + 4);
        float4 f2 = *(const float4*)(s + 8);
        float4 f3 = *(const float4*)(s + 12);
        float fv[16] = {f0.x, f0.y, f0.z, f0.w, f1.x, f1.y, f1.z, f1.w,
                        f2.x, f2.y, f2.z, f2.w, f3.x, f3.y, f3.z, f3.w};
        half8 h0, h1, l0, l1;
        #pragma unroll
        for (int i = 0; i < 8; i++) {
            _Float16 h = (_Float16)fv[i];
            h0[i] = h; l0[i] = (_Float16)(fv[i] - (float)h);
            h = (_Float16)fv[8 + i];
            h1[i] = h; l1[i] = (_Float16)(fv[8 + i] - (float)h);
        }
        *(half8*)&Khi[r * KP + ds]     = h0;
        *(half8*)&Khi[r * KP + ds + 8] = h1;
        *(half8*)&Klo[r * KP + ds]     = l0;
        *(half8*)&Klo[r * KP + ds + 8] = l1;
    };

    auto stageV = [&](int t0) {
        const int tp = tid >> 3;
        const int ds = (tid & 7) * 8;
        const float4* sa = (const float4*)(vp + (size_t)(t0 + 2 * tp) * ND + ds);
        const float4* sb = (const float4*)(vp + (size_t)(t0 + 2 * tp + 1) * ND + ds);
        float4 a0 = sa[0], a1 = sa[1];
        float4 b0 = sb[0], b1 = sb[1];
        float av[8] = {a0.x, a0.y, a0.z, a0.w, a1.x, a1.y, a1.z, a1.w};
        float bv[8] = {b0.x, b0.y, b0.z, b0.w, b1.x, b1.y, b1.z, b1.w};
        unsigned int* Vdw = (unsigned int*)Vsl;
        #pragma unroll
        for (int i = 0; i < 8; i++) {
            const int d  = ds + i;
            const int dw = d * (VP / 2) + (tp ^ (((d >> 3) & 7) << 2));
            union { _Float16 h[2]; unsigned int u; } pk;
            pk.h[0] = (_Float16)av[i];
            pk.h[1] = (_Float16)bv[i];
            Vdw[dw] = pk.u;
        }
    };

    float lsum[4] = {0.f, 0.f, 0.f, 0.f};

    for (int t0 = 0; t0 < NS; t0 += BN) {
        __syncthreads();
        stageK(t0);
        __syncthreads();
        #pragma unroll
        for (int n = 0; n < 4; n++) {
            const half8 kh0 = *(const half8*)&Khi[(n * 16 + lc) * KP + quad * 8];
            const half8 kh1 = *(const half8*)&Khi[(n * 16 + lc) * KP + quad * 8 + 32];
            const half8 kl0 = *(const half8*)&Klo[(n * 16 + lc) * KP + quad * 8];
            const half8 kl1 = *(const half8*)&Klo[(n * 16 + lc) * KP + quad * 8 + 32];
            f32x4 c = {0.f, 0.f, 0.f, 0.f};
            c = __builtin_amdgcn_mfma_f32_16x16x32_f16(aqh0, kh0, c, 0, 0, 0);
            c = __builtin_amdgcn_mfma_f32_16x16x32_f16(aqh1, kh1, c, 0, 0, 0);
            c = __builtin_amdgcn_mfma_f32_16x16x32_f16(aql0, kh0, c, 0, 0, 0);
            c = __builtin_amdgcn_mfma_f32_16x16x32_f16(aql1, kh1, c, 0, 0, 0);
            c = __builtin_amdgcn_mfma_f32_16x16x32_f16(aqh0, kl0, c, 0, 0, 0);
            c = __builtin_amdgcn_mfma_f32_16x16x32_f16(aqh1, kl1, c, 0, 0, 0);
            #pragma unroll
            for (int r2 = 0; r2 < 4; r2++) {
                const int lrow = wave * 16 + quad * 4 + r2;
                const int col  = t0 + n * 16 + lc;
                const float g = __expf(dp[(size_t)lrow * NS + col] * inv_s2);
                const float z = fabsf(c[r2] * g);
                lsum[r2] += __expf(z);
            }
        }
    }

    #pragma unroll
    for (int r2 = 0; r2 < 4; r2++) {
        float s = lsum[r2];
        s += __shfl_xor(s, 1, 64);
        s += __shfl_xor(s, 2, 64);
        s += __shfl_xor(s, 4, 64);
        s += __shfl_xor(s, 8, 64);
        lsum[r2] = 1.0f / s;
    }

    f32x4 o[4];
    #pragma unroll
    for (int i = 0; i < 4; i++) o[i] = (f32x4){0.f, 0.f, 0.f, 0.f};

    for (int t0 = 0; t0 < NS; t0 += BN) {
        __syncthreads();
        stageK(t0);
        stageV(t0);
        __syncthreads();
        #pragma unroll
        for (int n = 0; n < 4; n++) {
            const half8 kh0 = *(const half8*)&Khi[(n * 16 + lc) * KP + quad * 8];
            const half8 kh1 = *(const half8*)&Khi[(n * 16 + lc) * KP + quad * 8 + 32];
            const half8 kl0 = *(const half8*)&Klo[(n * 16 + lc) * KP + quad * 8];
            const half8 kl1 = *(const half8*)&Klo[(n * 16 + lc) * KP + quad * 8 + 32];
            f32x4 c = {0.f, 0.f, 0.f, 0.f};
            c = __builtin_amdgcn_mfma_f32_16x16x32_f16(aqh0, kh0, c, 0, 0, 0);
            c = __builtin_amdgcn_mfma_f32_16x16x32_f16(aqh1, kh1, c, 0, 0, 0);
            c = __builtin_amdgcn_mfma_f32_16x16x32_f16(aql0, kh0, c, 0, 0, 0);
            c = __builtin_amdgcn_mfma_f32_16x16x32_f16(aql1, kh1, c, 0, 0, 0);
            c = __builtin_amdgcn_mfma_f32_16x16x32_f16(aqh0, kl0, c, 0, 0, 0);
            c = __builtin_amdgcn_mfma_f32_16x16x32_f16(aqh1, kl1, c, 0, 0, 0);
            #pragma unroll
            for (int r2 = 0; r2 < 4; r2++) {
                const int lrow = wave * 16 + quad * 4 + r2;
                const int col  = t0 + n * 16 + lc;
                const float g = __expf(dp[(size_t)lrow * NS + col] * inv_s2);
                const float z = fabsf(c[r2] * g);
                const float p = __expf(z) * lsum[r2];
                Psl[(size_t)lrow * PP + n * 16 + lc] = (_Float16)p;
            }
        }
        const half8 pa0 = *(const half8*)&Psl[(wave * 16 + lc) * PP + quad * 8];
        const half8 pa1 = *(const half8*)&Psl[(wave * 16 + lc) * PP + quad * 8 + 32];

        {
            float* arow = ap + (size_t)(wave * 16 + lc) * NS + t0 + quad * 8;
            f32x4 s0 = {(float)pa0[0], (float)pa0[1], (float)pa0[2], (float)pa0[3]};
            f32x4 s1 = {(float)pa0[4], (float)pa0[5], (float)pa0[6], (float)pa0[7]};
            f32x4 s2 = {(float)pa1[0], (float)pa1[1], (float)pa1[2], (float)pa1[3]};
            f32x4 s3 = {(float)pa1[4], (float)pa1[5], (float)pa1[6], (float)pa1[7]};
            __builtin_nontemporal_store(s0, (f32x4*)arow);
            __builtin_nontemporal_store(s1, (f32x4*)(arow + 4));
            __builtin_nontemporal_store(s2, (f32x4*)(arow + 32));
            __builtin_nontemporal_store(s3, (f32x4*)(arow + 36));
        }

        #pragma unroll
        for (int n2 = 0; n2 < 4; n2++) {
            const int dv  = n2 * 16 + lc;
            const int fd  = ((dv >> 3) & 7) << 2;
            const int dwb = dv * (VP / 2);
            const half8 bv0 = *(const half8*)((const char*)Vsl +
                               (size_t)((dwb + ((quad * 4) ^ fd)) * 4));
            const half8 bv1 = *(const half8*)((const char*)Vsl +
                               (size_t)((dwb + ((16 + quad * 4) ^ fd)) * 4));
            o[n2] = __builtin_amdgcn_mfma_f32_16x16x32_f16(pa0, bv0, o[n2], 0, 0, 0);
            o[n2] = __builtin_amdgcn_mfma_f32_16x16x32_f16(pa1, bv1, o[n2], 0, 0, 0);
        }
    }

    #pragma unroll
    for (int n2 = 0; n2 < 4; n2++) {
        #pragma unroll
        for (int r2 = 0; r2 < 4; r2++) {
            const int lrow = wave * 16 + quad * 4 + r2;
            __builtin_nontemporal_store(o[n2][r2],
                                        &op[(size_t)lrow * ND + n2 * 16 + lc]);
        }
    }
}

extern "C" void kernel_launch(void* const* d_in, const int* in_sizes, int n_in,
                              void* d_out, int out_size, void* d_ws, size_t ws_size,
                              hipStream_t stream) {
    (void)in_sizes; (void)n_in; (void)out_size;
    const float* q   = (const float*)d_in[0];
    const float* k   = (const float*)d_in[1];
    const float* v   = (const float*)d_in[2];
    const float* dwm = (const float*)d_in[3];
    const float* sig = (const float*)d_in[4];
    float* out0 = (float*)d_out;
    float* attn = out0 + (size_t)NB * NH * NS * ND;

    if (d_ws != nullptr && ws_size >= KV_BYTES) {
        char* ws = (char*)d_ws;
        prep_kv<<<dim3(NT, NB * NH), dim3(256), 0, stream>>>(k, v, ws);
        attn_fused<<<dim3(NS / BM, NB * NH), dim3(256), 0, stream>>>(
            q, ws, dwm, sig, out0, attn);
    } else {
        dim3 grid(NS / BM, NB * NH);
        attn_fused_legacy<<<grid, dim3(256), 0, stream>>>(
            q, k, v, dwm, sig, out0, attn);
    }
}

// Round 4
// 850.904 us; speedup vs baseline: 1.0387x; 1.0164x over previous
//
#include <hip/hip_runtime.h>
#include <hip/hip_fp16.h>

// Problem constants
#define NB 2
#define NH 16
#define NS 2048
#define ND 64
#define BM 64
#define BN 64
#define NT (NS / BN)            // 32 K/V tiles
#define TILE_BYTES 24576        // Khi 8K + Klo 8K + Vt 8K per (bh,tile)
#define KV_BYTES ((size_t)NB * NH * NT * TILE_BYTES)   // 24 MiB workspace

// XOR swizzle: f(r) = (r&7) ^ ((r&8)>>2), applied to 16B-slot bits (4..6).
// Verified conflict-free in rounds 2/3 (SQ_LDS_BANK_CONFLICT == 0).
#define SW(r) ((((r) & 7) ^ (((r) & 8) >> 2)) << 4)

typedef _Float16 half8 __attribute__((ext_vector_type(8)));
typedef _Float16 half4 __attribute__((ext_vector_type(4)));
typedef float f32x4 __attribute__((ext_vector_type(4)));

#define GLDS16(gp, lp) __builtin_amdgcn_global_load_lds(                      \
    (const __attribute__((address_space(1))) void*)(gp),                      \
    (__attribute__((address_space(3))) void*)(lp), 16, 0, 0)

// ---------------------------------------------------------------------------
// Prep: build per-(bh,tile) LDS-image blobs in workspace:
//   +0     : K hi fp16, rows=t (64), 128B/row, 16B slots XOR-swizzled
//   +8192  : K lo fp16 (residual), same layout
//   +16384 : V transposed fp16 (rows = d, cols = t), same layout
// ---------------------------------------------------------------------------
__global__ __launch_bounds__(256)
void prep_kv(const float* __restrict__ kg, const float* __restrict__ vg,
             char* __restrict__ ws)
{
    __shared__ _Float16 T[64][72];   // V tile staged t-major for transpose
    const int tile = blockIdx.x, bh = blockIdx.y, tid = threadIdx.x;
    const float* kp = kg + ((size_t)bh * NS + (size_t)tile * BN) * ND;
    const float* vp = vg + ((size_t)bh * NS + (size_t)tile * BN) * ND;
    char* img = ws + ((size_t)(bh * NT + tile)) * TILE_BYTES;

    // K hi/lo split (identical numerics to the in-loop split it replaces)
    #pragma unroll
    for (int i = 0; i < 2; ++i) {
        const int c = tid + i * 256;          // 512 chunks of 8 elems
        const int r = c >> 3, s = c & 7;
        const float* src = kp + r * ND + s * 8;
        float4 f0 = *(const float4*)src;
        float4 f1 = *(const float4*)(src + 4);
        float fv[8] = {f0.x, f0.y, f0.z, f0.w, f1.x, f1.y, f1.z, f1.w};
        half8 h, l;
        #pragma unroll
        for (int j = 0; j < 8; ++j) {
            _Float16 hh = (_Float16)fv[j];
            h[j] = hh; l[j] = (_Float16)(fv[j] - (float)hh);
        }
        const int off = r * 128 + ((s << 4) ^ SW(r));
        *(half8*)(img + off) = h;
        *(half8*)(img + 8192 + off) = l;
    }
    // V -> LDS (t-major), then write transposed (d-major) swizzled image
    #pragma unroll
    for (int i = 0; i < 2; ++i) {
        const int c = tid + i * 256;
        const int t = c >> 3, ds = (c & 7) * 8;
        const float* src = vp + t * ND + ds;
        float4 f0 = *(const float4*)src;
        float4 f1 = *(const float4*)(src + 4);
        float fv[8] = {f0.x, f0.y, f0.z, f0.w, f1.x, f1.y, f1.z, f1.w};
        #pragma unroll
        for (int j = 0; j < 8; ++j) T[t][ds + j] = (_Float16)fv[j];
    }
    __syncthreads();
    #pragma unroll
    for (int i = 0; i < 2; ++i) {
        const int c = tid + i * 256;
        const int d = c >> 3, s = c & 7;
        half8 h;
        #pragma unroll
        for (int j = 0; j < 8; ++j) h[j] = T[s * 8 + j][d];
        *(half8*)(img + 16384 + d * 128 + ((s << 4) ^ SW(d))) = h;
    }
}

// ---------------------------------------------------------------------------
// Main fused kernel, round 4: 2-phase software pipeline (T3/T4-lite).
//  - K images (16 KB: hi|lo) double-buffered; tile t+1's global_load_lds
//    issued BEFORE computing tile t -> HBM/L3 latency hidden under compute.
//  - V single-buffered, issued at tile top (oldest in vmcnt queue), drained
//    with counted vmcnt(4) pre-PV so the K-prefetch stays in flight.
//  - raw s_barrier + explicit asm waitcnt (NEVER __syncthreads in the loop:
//    it force-drains vmcnt(0) and kills the overlap).
// LDS = 48 KB -> 3 blocks/CU. Grid stays natural 2D (round-3 dwm locality).
// ---------------------------------------------------------------------------
__global__ __launch_bounds__(256, 3)
void attn_fused(const float* __restrict__ qg, const char* __restrict__ kvws,
                const float* __restrict__ dwm, const float* __restrict__ sig,
                float* __restrict__ out0, float* __restrict__ attn)
{
    __shared__ char lds[49152];
    // [0,16K)  K buffer 0 (hi 8K | lo 8K)
    // [16,32K) K buffer 1
    // [32,40K) V^T image
    // [40,48K) Ps (wave-private 16-row bands)
    char* const Vs = lds + 32768;
    char* const Ps = lds + 40960;

    const int tid  = threadIdx.x;
    const int wave = tid >> 6;
    const int lane = tid & 63;
    const int quad = lane >> 4;
    const int lc   = lane & 15;

    const int mtile = blockIdx.x;   // 0..31 row tiles
    const int bh    = blockIdx.y;   // 0..31 (b,h)
    const int b     = bh >> 4;

    const float sv = sig[0];
    const float inv_s2 = 1.0f / (sv * sv);

    const float* qp  = qg  + (size_t)bh * NS * ND + (size_t)mtile * BM * ND;
    const char*  kvb = kvws + (size_t)bh * NT * TILE_BYTES;
    const float* dp  = dwm + (size_t)b  * NS * NS + (size_t)mtile * BM * NS;
    float* op = out0 + (size_t)bh * NS * ND + (size_t)mtile * BM * ND;
    float* ap = attn + (size_t)bh * NS * NS + (size_t)mtile * BM * NS;

    // ---- Q A-fragments, hi/lo fp16 split (once per block) ----
    half8 aqh0, aql0, aqh1, aql1;
    {
        const float* qr = qp + (size_t)(wave * 16 + lc) * ND + quad * 8;
        float4 f0 = *(const float4*)qr;
        float4 f1 = *(const float4*)(qr + 4);
        float4 f2 = *(const float4*)(qr + 32);
        float4 f3 = *(const float4*)(qr + 36);
        float v0[8] = {f0.x, f0.y, f0.z, f0.w, f1.x, f1.y, f1.z, f1.w};
        float v1[8] = {f2.x, f2.y, f2.z, f2.w, f3.x, f3.y, f3.z, f3.w};
        #pragma unroll
        for (int j = 0; j < 8; j++) {
            float x = v0[j] * 0.125f;           // 1/TEMPERATURE
            _Float16 h = (_Float16)x;
            aqh0[j] = h; aql0[j] = (_Float16)(x - (float)h);
            x = v1[j] * 0.125f;
            h = (_Float16)x;
            aqh1[j] = h; aql1[j] = (_Float16)(x - (float)h);
        }
    }

    // ================= PASS A: row sums l = sum_t exp(|s*g|) ================
    float lsum[4] = {0.f, 0.f, 0.f, 0.f};

    // prologue: stage K(0) -> buf0, full drain
    {
        #pragma unroll
        for (int j = 0; j < 4; ++j)
            GLDS16(kvb + j * 4096 + tid * 16, lds + j * 4096 + tid * 16);
        asm volatile("s_waitcnt vmcnt(0)" ::: "memory");
        __builtin_amdgcn_s_barrier();
    }

    for (int t = 0; t < NT; ++t) {
        char* const kb = lds + ((t & 1) << 14);
        if (t + 1 < NT) {   // prefetch K(t+1) into the other buffer
            const char* nimg = kvb + (size_t)(t + 1) * TILE_BYTES;
            char* nb = lds + (((t + 1) & 1) << 14);
            #pragma unroll
            for (int j = 0; j < 4; ++j)
                GLDS16(nimg + j * 4096 + tid * 16, nb + j * 4096 + tid * 16);
        }
        #pragma unroll
        for (int n = 0; n < 4; ++n) {
            const int rowK = n * 16 + lc;
            const int sw = SW(rowK);
            const char* kkb = kb + rowK * 128;
            const char* llb = kb + 8192 + rowK * 128;
            const half8 kh0 = *(const half8*)(kkb + ((quad * 16) ^ sw));
            const half8 kh1 = *(const half8*)(kkb + ((64 + quad * 16) ^ sw));
            const half8 kl0 = *(const half8*)(llb + ((quad * 16) ^ sw));
            const half8 kl1 = *(const half8*)(llb + ((64 + quad * 16) ^ sw));
            f32x4 c = {0.f, 0.f, 0.f, 0.f};
            c = __builtin_amdgcn_mfma_f32_16x16x32_f16(aqh0, kh0, c, 0, 0, 0);
            c = __builtin_amdgcn_mfma_f32_16x16x32_f16(aqh1, kh1, c, 0, 0, 0);
            c = __builtin_amdgcn_mfma_f32_16x16x32_f16(aql0, kh0, c, 0, 0, 0);
            c = __builtin_amdgcn_mfma_f32_16x16x32_f16(aql1, kh1, c, 0, 0, 0);
            c = __builtin_amdgcn_mfma_f32_16x16x32_f16(aqh0, kl0, c, 0, 0, 0);
            c = __builtin_amdgcn_mfma_f32_16x16x32_f16(aqh1, kl1, c, 0, 0, 0);
            #pragma unroll
            for (int r2 = 0; r2 < 4; ++r2) {
                const int lrow = wave * 16 + quad * 4 + r2;
                const int col  = t * BN + n * 16 + lc;
                const float g = __expf(dp[(size_t)lrow * NS + col] * inv_s2);
                lsum[r2] += __expf(fabsf(c[r2]) * g);   // z <= ~16: fp32-safe
            }
        }
        // drain my prefetch (mostly complete by now) so all waves see K(t+1)
        asm volatile("s_waitcnt vmcnt(0)" ::: "memory");
        __builtin_amdgcn_s_barrier();
    }

    #pragma unroll
    for (int r2 = 0; r2 < 4; ++r2) {
        float s = lsum[r2];
        s += __shfl_xor(s, 1, 64);
        s += __shfl_xor(s, 2, 64);
        s += __shfl_xor(s, 4, 64);
        s += __shfl_xor(s, 8, 64);
        lsum[r2] = 1.0f / s;   // 1/l
    }

    // ============ PASS B: recompute scores, write attn, O += P*V ============
    f32x4 o[4];
    #pragma unroll
    for (int i = 0; i < 4; i++) o[i] = (f32x4){0.f, 0.f, 0.f, 0.f};

    // prologue: stage K(0) -> buf0, full drain (V(0) issued inside iter 0)
    {
        #pragma unroll
        for (int j = 0; j < 4; ++j)
            GLDS16(kvb + j * 4096 + tid * 16, lds + j * 4096 + tid * 16);
        asm volatile("s_waitcnt vmcnt(0)" ::: "memory");
        __builtin_amdgcn_s_barrier();
    }

    for (int t = 0; t < NT; ++t) {
        const char* img = kvb + (size_t)t * TILE_BYTES;
        char* const kb = lds + ((t & 1) << 14);

        // V(t) -> Vs, issued FIRST (oldest in the in-order vmcnt queue);
        // safe: all waves finished PV(t-1) at the previous end barrier.
        GLDS16(img + 16384 +        tid * 16, Vs +        tid * 16);
        GLDS16(img + 16384 + 4096 + tid * 16, Vs + 4096 + tid * 16);
        if (t + 1 < NT) {   // prefetch K(t+1)
            const char* nimg = kvb + (size_t)(t + 1) * TILE_BYTES;
            char* nb = lds + (((t + 1) & 1) << 14);
            #pragma unroll
            for (int j = 0; j < 4; ++j)
                GLDS16(nimg + j * 4096 + tid * 16, nb + j * 4096 + tid * 16);
        }

        // ---- QK^T + softmax + Ps (reads kb; V latency hides under this) ----
        #pragma unroll
        for (int n = 0; n < 4; ++n) {
            const int rowK = n * 16 + lc;
            const int sw = SW(rowK);
            const char* kkb = kb + rowK * 128;
            const char* llb = kb + 8192 + rowK * 128;
            const half8 kh0 = *(const half8*)(kkb + ((quad * 16) ^ sw));
            const half8 kh1 = *(const half8*)(kkb + ((64 + quad * 16) ^ sw));
            const half8 kl0 = *(const half8*)(llb + ((quad * 16) ^ sw));
            const half8 kl1 = *(const half8*)(llb + ((64 + quad * 16) ^ sw));
            f32x4 c = {0.f, 0.f, 0.f, 0.f};
            c = __builtin_amdgcn_mfma_f32_16x16x32_f16(aqh0, kh0, c, 0, 0, 0);
            c = __builtin_amdgcn_mfma_f32_16x16x32_f16(aqh1, kh1, c, 0, 0, 0);
            c = __builtin_amdgcn_mfma_f32_16x16x32_f16(aql0, kh0, c, 0, 0, 0);
            c = __builtin_amdgcn_mfma_f32_16x16x32_f16(aql1, kh1, c, 0, 0, 0);
            c = __builtin_amdgcn_mfma_f32_16x16x32_f16(aqh0, kl0, c, 0, 0, 0);
            c = __builtin_amdgcn_mfma_f32_16x16x32_f16(aqh1, kl1, c, 0, 0, 0);
            #pragma unroll
            for (int r2 = 0; r2 < 4; ++r2) {
                const int lrow = wave * 16 + quad * 4 + r2;
                const int col  = t * BN + n * 16 + lc;
                const float g = __expf(dp[(size_t)lrow * NS + col] * inv_s2);
                const float p = __expf(fabsf(c[r2]) * g) * lsum[r2];
                *(_Float16*)(Ps + lrow * 128 +
                             (((n * 16 + lc) * 2) ^ SW(lrow))) = (_Float16)p;
            }
        }

        // V(t) complete for all waves; keep K(t+1) (4 loads) in flight.
        if (t + 1 < NT) { asm volatile("s_waitcnt vmcnt(4)" ::: "memory"); }
        else            { asm volatile("s_waitcnt vmcnt(0)" ::: "memory"); }
        __builtin_amdgcn_s_barrier();

        // P: C-layout -> A-layout via wave-private swizzled band
        const int rowP = wave * 16 + lc;
        const int swp = SW(rowP);
        const half8 pa0 = *(const half8*)(Ps + rowP * 128 + ((quad * 16) ^ swp));
        const half8 pa1 = *(const half8*)(Ps + rowP * 128 + ((64 + quad * 16) ^ swp));

        // attn store: 16 lanes cover one row's 64 cols -> 256B contiguous runs
        {
            const int cl = lane & 15, rh = lane >> 4;
            #pragma unroll
            for (int g2 = 0; g2 < 4; ++g2) {
                const int row = wave * 16 + g2 * 4 + rh;
                const half4 ph = *(const half4*)(Ps + row * 128 +
                                                 ((cl * 8) ^ SW(row)));
                f32x4 s = {(float)ph[0], (float)ph[1], (float)ph[2], (float)ph[3]};
                __builtin_nontemporal_store(
                    s, (f32x4*)(ap + (size_t)row * NS + t * BN + cl * 4));
            }
        }

        #pragma unroll
        for (int n2 = 0; n2 < 4; ++n2) {
            const int dv = n2 * 16 + lc;
            const int swv = SW(dv);
            const char* vb = Vs + dv * 128;
            const half8 bv0 = *(const half8*)(vb + ((quad * 16) ^ swv));
            const half8 bv1 = *(const half8*)(vb + ((64 + quad * 16) ^ swv));
            o[n2] = __builtin_amdgcn_mfma_f32_16x16x32_f16(pa0, bv0, o[n2], 0, 0, 0);
            o[n2] = __builtin_amdgcn_mfma_f32_16x16x32_f16(pa1, bv1, o[n2], 0, 0, 0);
        }

        // K(t+1) (and this tile's attn stores) retired; Vs/kb free for reuse.
        asm volatile("s_waitcnt vmcnt(0)" ::: "memory");
        __builtin_amdgcn_s_barrier();
    }

    // ---- epilogue: write O ----
    #pragma unroll
    for (int n2 = 0; n2 < 4; ++n2) {
        #pragma unroll
        for (int r2 = 0; r2 < 4; ++r2) {
            const int lrow = wave * 16 + quad * 4 + r2;
            __builtin_nontemporal_store(o[n2][r2],
                                        &op[(size_t)lrow * ND + n2 * 16 + lc]);
        }
    }
}

// ---------------------------------------------------------------------------
// Legacy fallback (previous verified kernel, verbatim) — used only if the
// provided workspace is too small for the KV tile images.
// ---------------------------------------------------------------------------
#define KP 72
#define VP 72
#define PP 72

__global__ __launch_bounds__(256, 4)
void attn_fused_legacy(const float* __restrict__ qg, const float* __restrict__ kgl,
                       const float* __restrict__ vgl, const float* __restrict__ dwm,
                       const float* __restrict__ sig, float* __restrict__ out0,
                       float* __restrict__ attn)
{
    __shared__ _Float16 Khi[BN * KP];
    __shared__ _Float16 Klo[BN * KP];
    __shared__ _Float16 Vsl[ND * VP];
    __shared__ _Float16 Psl[BM * PP];

    const int tid  = threadIdx.x;
    const int wave = tid >> 6;
    const int lane = tid & 63;
    const int quad = lane >> 4;
    const int lc   = lane & 15;

    const int mtile = blockIdx.x;
    const int bh    = blockIdx.y;
    const int b     = bh >> 4;

    const float sv = sig[0];
    const float inv_s2 = 1.0f / (sv * sv);

    const float* qp = qg  + (size_t)bh * NS * ND + (size_t)mtile * BM * ND;
    const float* kp = kgl + (size_t)bh * NS * ND;
    const float* vp = vgl + (size_t)bh * NS * ND;
    const float* dp = dwm + (size_t)b  * NS * NS + (size_t)mtile * BM * NS;
    float* op = out0 + (size_t)bh * NS * ND + (size_t)mtile * BM * ND;
    float* ap = attn + (size_t)bh * NS * NS + (size_t)mtile * BM * NS;

    half8 aqh0, aql0, aqh1, aql1;
    {
        const float* qr = qp + (size_t)(wave * 16 + lc) * ND + quad * 8;
        float4 f0 = *(const float4*)qr;
        float4 f1 = *(const float4*)(qr + 4);
        float4 f2 = *(const float4*)(qr + 32);
        float4 f3 = *(const float4*)(qr + 36);
        float v0[8] = {f0.x, f0.y, f0.z, f0.w, f1.x, f1.y, f1.z, f1.w};
        float v1[8] = {f2.x, f2.y, f2.z, f2.w, f3.x, f3.y, f3.z, f3.w};
        #pragma unroll
        for (int j = 0; j < 8; j++) {
            float x = v0[j] * 0.125f;
            _Float16 h = (_Float16)x;
            aqh0[j] = h; aql0[j] = (_Float16)(x - (float)h);
            x = v1[j] * 0.125f;
            h = (_Float16)x;
            aqh1[j] = h; aql1[j] = (_Float16)(x - (float)h);
        }
    }

    auto stageK = [&](int t0) {
        const int r  = tid >> 2;
        const int ds = (tid & 3) * 16;
        const float* s = kp + (size_t)(t0 + r) * ND + ds;
        float4 f0 = *(const float4*)s;
        float4 f1 = *(const float4*)(s + 4);
        float4 f2 = *(const float4*)(s + 8);
        float4 f3 = *(const float4*)(s + 12);
        float fv[16] = {f0.x, f0.y, f0.z, f0.w, f1.x, f1.y, f1.z, f1.w,
                        f2.x, f2.y, f2.z, f2.w, f3.x, f3.y, f3.z, f3.w};
        half8 h0, h1, l0, l1;
        #pragma unroll
        for (int i = 0; i < 8; i++) {
            _Float16 h = (_Float16)fv[i];
            h0[i] = h; l0[i] = (_Float16)(fv[i] - (float)h);
            h = (_Float16)fv[8 + i];
            h1[i] = h; l1[i] = (_Float16)(fv[8 + i] - (float)h);
        }
        *(half8*)&Khi[r * KP + ds]     = h0;
        *(half8*)&Khi[r * KP + ds + 8] = h1;
        *(half8*)&Klo[r * KP + ds]     = l0;
        *(half8*)&Klo[r * KP + ds + 8] = l1;
    };

    auto stageV = [&](int t0) {
        const int tp = tid >> 3;
        const int ds = (tid & 7) * 8;
        const float4* sa = (const float4*)(vp + (size_t)(t0 + 2 * tp) * ND + ds);
        const float4* sb = (const float4*)(vp + (size_t)(t0 + 2 * tp + 1) * ND + ds);
        float4 a0 = sa[0], a1 = sa[1];
        float4 b0 = sb[0], b1 = sb[1];
        float av[8] = {a0.x, a0.y, a0.z, a0.w, a1.x, a1.y, a1.z, a1.w};
        float bv[8] = {b0.x, b0.y, b0.z, b0.w, b1.x, b1.y, b1.z, b1.w};
        unsigned int* Vdw = (unsigned int*)Vsl;
        #pragma unroll
        for (int i = 0; i < 8; i++) {
            const int d  = ds + i;
            const int dw = d * (VP / 2) + (tp ^ (((d >> 3) & 7) << 2));
            union { _Float16 h[2]; unsigned int u; } pk;
            pk.h[0] = (_Float16)av[i];
            pk.h[1] = (_Float16)bv[i];
            Vdw[dw] = pk.u;
        }
    };

    float lsum[4] = {0.f, 0.f, 0.f, 0.f};

    for (int t0 = 0; t0 < NS; t0 += BN) {
        __syncthreads();
        stageK(t0);
        __syncthreads();
        #pragma unroll
        for (int n = 0; n < 4; n++) {
            const half8 kh0 = *(const half8*)&Khi[(n * 16 + lc) * KP + quad * 8];
            const half8 kh1 = *(const half8*)&Khi[(n * 16 + lc) * KP + quad * 8 + 32];
            const half8 kl0 = *(const half8*)&Klo[(n * 16 + lc) * KP + quad * 8];
            const half8 kl1 = *(const half8*)&Klo[(n * 16 + lc) * KP + quad * 8 + 32];
            f32x4 c = {0.f, 0.f, 0.f, 0.f};
            c = __builtin_amdgcn_mfma_f32_16x16x32_f16(aqh0, kh0, c, 0, 0, 0);
            c = __builtin_amdgcn_mfma_f32_16x16x32_f16(aqh1, kh1, c, 0, 0, 0);
            c = __builtin_amdgcn_mfma_f32_16x16x32_f16(aql0, kh0, c, 0, 0, 0);
            c = __builtin_amdgcn_mfma_f32_16x16x32_f16(aql1, kh1, c, 0, 0, 0);
            c = __builtin_amdgcn_mfma_f32_16x16x32_f16(aqh0, kl0, c, 0, 0, 0);
            c = __builtin_amdgcn_mfma_f32_16x16x32_f16(aqh1, kl1, c, 0, 0, 0);
            #pragma unroll
            for (int r2 = 0; r2 < 4; r2++) {
                const int lrow = wave * 16 + quad * 4 + r2;
                const int col  = t0 + n * 16 + lc;
                const float g = __expf(dp[(size_t)lrow * NS + col] * inv_s2);
                const float z = fabsf(c[r2] * g);
                lsum[r2] += __expf(z);
            }
        }
    }

    #pragma unroll
    for (int r2 = 0; r2 < 4; r2++) {
        float s = lsum[r2];
        s += __shfl_xor(s, 1, 64);
        s += __shfl_xor(s, 2, 64);
        s += __shfl_xor(s, 4, 64);
        s += __shfl_xor(s, 8, 64);
        lsum[r2] = 1.0f / s;
    }

    f32x4 o[4];
    #pragma unroll
    for (int i = 0; i < 4; i++) o[i] = (f32x4){0.f, 0.f, 0.f, 0.f};

    for (int t0 = 0; t0 < NS; t0 += BN) {
        __syncthreads();
        stageK(t0);
        stageV(t0);
        __syncthreads();
        #pragma unroll
        for (int n = 0; n < 4; n++) {
            const half8 kh0 = *(const half8*)&Khi[(n * 16 + lc) * KP + quad * 8];
            const half8 kh1 = *(const half8*)&Khi[(n * 16 + lc) * KP + quad * 8 + 32];
            const half8 kl0 = *(const half8*)&Klo[(n * 16 + lc) * KP + quad * 8];
            const half8 kl1 = *(const half8*)&Klo[(n * 16 + lc) * KP + quad * 8 + 32];
            f32x4 c = {0.f, 0.f, 0.f, 0.f};
            c = __builtin_amdgcn_mfma_f32_16x16x32_f16(aqh0, kh0, c, 0, 0, 0);
            c = __builtin_amdgcn_mfma_f32_16x16x32_f16(aqh1, kh1, c, 0, 0, 0);
            c = __builtin_amdgcn_mfma_f32_16x16x32_f16(aql0, kh0, c, 0, 0, 0);
            c = __builtin_amdgcn_mfma_f32_16x16x32_f16(aql1, kh1, c, 0, 0, 0);
            c = __builtin_amdgcn_mfma_f32_16x16x32_f16(aqh0, kl0, c, 0, 0, 0);
            c = __builtin_amdgcn_mfma_f32_16x16x32_f16(aqh1, kl1, c, 0, 0, 0);
            #pragma unroll
            for (int r2 = 0; r2 < 4; r2++) {
                const int lrow = wave * 16 + quad * 4 + r2;
                const int col  = t0 + n * 16 + lc;
                const float g = __expf(dp[(size_t)lrow * NS + col] * inv_s2);
                const float z = fabsf(c[r2] * g);
                const float p = __expf(z) * lsum[r2];
                Psl[(size_t)lrow * PP + n * 16 + lc] = (_Float16)p;
            }
        }
        const half8 pa0 = *(const half8*)&Psl[(wave * 16 + lc) * PP + quad * 8];
        const half8 pa1 = *(const half8*)&Psl[(wave * 16 + lc) * PP + quad * 8 + 32];

        {
            float* arow = ap + (size_t)(wave * 16 + lc) * NS + t0 + quad * 8;
            f32x4 s0 = {(float)pa0[0], (float)pa0[1], (float)pa0[2], (float)pa0[3]};
            f32x4 s1 = {(float)pa0[4], (float)pa0[5], (float)pa0[6], (float)pa0[7]};
            f32x4 s2 = {(float)pa1[0], (float)pa1[1], (float)pa1[2], (float)pa1[3]};
            f32x4 s3 = {(float)pa1[4], (float)pa1[5], (float)pa1[6], (float)pa1[7]};
            __builtin_nontemporal_store(s0, (f32x4*)arow);
            __builtin_nontemporal_store(s1, (f32x4*)(arow + 4));
            __builtin_nontemporal_store(s2, (f32x4*)(arow + 32));
            __builtin_nontemporal_store(s3, (f32x4*)(arow + 36));
        }

        #pragma unroll
        for (int n2 = 0; n2 < 4; n2++) {
            const int dv  = n2 * 16 + lc;
            const int fd  = ((dv >> 3) & 7) << 2;
            const int dwb = dv * (VP / 2);
            const half8 bv0 = *(const half8*)((const char*)Vsl +
                               (size_t)((dwb + ((quad * 4) ^ fd)) * 4));
            const half8 bv1 = *(const half8*)((const char*)Vsl +
                               (size_t)((dwb + ((16 + quad * 4) ^ fd)) * 4));
            o[n2] = __builtin_amdgcn_mfma_f32_16x16x32_f16(pa0, bv0, o[n2], 0, 0, 0);
            o[n2] = __builtin_amdgcn_mfma_f32_16x16x32_f16(pa1, bv1, o[n2], 0, 0, 0);
        }
    }

    #pragma unroll
    for (int n2 = 0; n2 < 4; n2++) {
        #pragma unroll
        for (int r2 = 0; r2 < 4; r2++) {
            const int lrow = wave * 16 + quad * 4 + r2;
            __builtin_nontemporal_store(o[n2][r2],
                                        &op[(size_t)lrow * ND + n2 * 16 + lc]);
        }
    }
}

extern "C" void kernel_launch(void* const* d_in, const int* in_sizes, int n_in,
                              void* d_out, int out_size, void* d_ws, size_t ws_size,
                              hipStream_t stream) {
    (void)in_sizes; (void)n_in; (void)out_size;
    const float* q   = (const float*)d_in[0];
    const float* k   = (const float*)d_in[1];
    const float* v   = (const float*)d_in[2];
    const float* dwm = (const float*)d_in[3];
    const float* sig = (const float*)d_in[4];
    float* out0 = (float*)d_out;
    float* attn = out0 + (size_t)NB * NH * NS * ND;

    if (d_ws != nullptr && ws_size >= KV_BYTES) {
        char* ws = (char*)d_ws;
        prep_kv<<<dim3(NT, NB * NH), dim3(256), 0, stream>>>(k, v, ws);
        attn_fused<<<dim3(NS / BM, NB * NH), dim3(256), 0, stream>>>(
            q, ws, dwm, sig, out0, attn);
    } else {
        dim3 grid(NS / BM, NB * NH);
        attn_fused_legacy<<<grid, dim3(256), 0, stream>>>(
            q, k, v, dwm, sig, out0, attn);
    }
}